// Round 11
// baseline (3294.211 us; speedup 1.0000x reference)
//
#include <hip/hip_runtime.h>
#include <stdint.h>

#define NPER 8192
#define NB 4
#define MPER 4096
#define MTOT (NB*MPER)      // 16384
#define KNB 64
#define CIN 64
#define R2C 0.04f           // f32-nearest of python 0.2*0.2 (NOT 0.2f*0.2f!)

// d_out (floats): x_out [MTOT*128] | pos_out [MTOT*3] | batch_out [MTOT]
#define POSOUT_OFF (MTOT*128)
#define BATCH_OFF  (MTOT*128 + MTOT*3)

// ws: nbr u16 [MTOT*64] @0 (2MB) | cnt i32 [MTOT] @2MB (64KB) |
//     precomp f32[32768*64] @PRE_OFF (8MB, optional: ws_size-gated)
#define PRE_OFF 2162688ull
#define PRE_BYTES 8388608ull

// fps->radius scratch in x_out region of d_out (free until k_conv):
// per cloud stride SSTR floats: SX[8192] @0 | SY @8192 | SZ @16384 |
// SO u16[8192] @24576f | CS u32[513] @28672f   (sorted by lex cell)
#define SSTR 30720

typedef float v2f __attribute__((ext_vector_type(2)));

// ---------------------------------------------------------------- K1: FPS
// R10 exact lazy FPS + two tail optimizations:
//  (1) coords in packed float4 LDS (orig idx in .w): winner fetch = ONE
//      ds_read_b128 broadcast (was 3 dependent ds_reads).
//  (2) 2-level winner reduce: wave wv -> atomicMax slot[phase][wv&3]
//      (4-way contention instead of 16-way same-address serialization);
//      post-barrier all threads read 4 u64 + 3 maxes.
// Everything else proven: 1024 thr, 8 pts/thread lex-cell-sorted, AABB
// prune w/ fresh lmax (provably-exact skip: 1.2e-4 margin >> 5e-7 f32
// rounding), bitwise-numpy update ((dx*dx+dy*dy)+dz*dz, rn, no fma),
// key=(bd<<26)|brk (max d2, tie -> min orig = np.argmax first-max),
// DPP wave max + single-owner readlane, ONE barrier/iter.
#define FPS_T 1024
#define PTS 8
#define NCELL 512

// dynamic-LDS layout (bytes)
#define OFF_XYZ4 0                        // float4[8192] = 131072
#define OFF_WIN  (OFF_XYZ4 + NPER*16)     // 131072: u16[4096]; hist/scan overlay
#define OFF_SLOT (OFF_WIN + MPER*2)       // 139264: u64[12] (3 phases x 4)
#define OFF_SID0 (OFF_SLOT + 96)          // 139360
#define FPS_LDS  (OFF_SID0 + 16)          // 139376 B

template<int CTRL>
__device__ __forceinline__ unsigned dppmax(unsigned v) {
  unsigned t = (unsigned)__builtin_amdgcn_update_dpp(
      0, (int)v, CTRL, 0xf, 0xf, true);   // bound_ctrl: OOB lanes read 0
  return v > t ? v : t;
}
__device__ __forceinline__ unsigned wave_max_u32(unsigned v) {
  v = dppmax<0x111>(v);   // row_shr:1
  v = dppmax<0x112>(v);   // row_shr:2
  v = dppmax<0x114>(v);   // row_shr:4
  v = dppmax<0x118>(v);   // row_shr:8
  v = dppmax<0x142>(v);   // row_bcast15
  v = dppmax<0x143>(v);   // row_bcast31
  return (unsigned)__builtin_amdgcn_readlane((int)v, 63);
}

__global__ __launch_bounds__(1024) void k_fps(const float* __restrict__ pos,
                                              float* __restrict__ dout)
{
#pragma clang fp contract(off)
  extern __shared__ char smem[];
  float4* X4 = (float4*)(smem + OFF_XYZ4);
  unsigned short* winb = (unsigned short*)(smem + OFF_WIN);
  unsigned* hist = (unsigned*)(smem + OFF_WIN);            // setup-only overlay
  unsigned* scanb = (unsigned*)(smem + OFF_WIN + 2048);    // setup-only overlay
  unsigned long long* slot12 = (unsigned long long*)(smem + OFF_SLOT);
  unsigned* sid0p = (unsigned*)(smem + OFF_SID0);

  const int b = blockIdx.x;
  const int tid = threadIdx.x;
  const int wv = tid >> 6;
  const float* pb = pos + (size_t)b * NPER * 3;
  float* qo = dout + POSOUT_OFF + (size_t)b * MPER * 3;
  float* scrb = dout + (size_t)b * SSTR;
  float* gSX = scrb; float* gSY = scrb + 8192; float* gSZ = scrb + 16384;
  unsigned* gSO = (unsigned*)(scrb + 24576);       // packed u16 pairs
  unsigned* gCS = (unsigned*)(scrb + 28672);       // 513 entries

  if (tid < NCELL) hist[tid] = 0u;
  if (tid < 12) slot12[tid] = 0ull;
  __syncthreads();

  // ---- sort pass 1: count (lex cell) ----
  float sxv[PTS], syv[PTS], szv[PTS];
  unsigned cellv[PTS];
#pragma unroll
  for (int k = 0; k < PTS; ++k) {
    int i = k * FPS_T + tid;
    sxv[k] = pb[i*3+0]; syv[k] = pb[i*3+1]; szv[k] = pb[i*3+2];
    unsigned ix = min(7u, (unsigned)(int)(sxv[k] * 8.0f));
    unsigned iy = min(7u, (unsigned)(int)(syv[k] * 8.0f));
    unsigned iz = min(7u, (unsigned)(int)(szv[k] * 8.0f));
    cellv[k] = (ix << 6) | (iy << 3) | iz;
    atomicAdd(&hist[cellv[k]], 1u);
  }
  __syncthreads();
  // ---- scan -> exclusive starts; export CS to global ----
  if (tid < NCELL) scanb[tid] = hist[tid];
  __syncthreads();
  for (int s = 1; s < NCELL; s <<= 1) {
    unsigned v = 0u;
    if (tid >= s && tid < NCELL) v = scanb[tid - s];
    __syncthreads();
    if (tid >= s && tid < NCELL) scanb[tid] += v;
    __syncthreads();
  }
  if (tid < NCELL) {
    hist[tid] = scanb[tid] - hist[tid];   // exclusive start
    gCS[tid+1] = scanb[tid];              // start of cell tid+1
  }
  if (tid == 0) gCS[0] = 0u;
  __syncthreads();
  // ---- sort pass 2: scatter (x,y,z,orig) into LDS float4 ----
#pragma unroll
  for (int k = 0; k < PTS; ++k) {
    unsigned dst = atomicAdd(&hist[cellv[k]], 1u);
    int orig = k * FPS_T + tid;
    float4 v;
    v.x = sxv[k]; v.y = syv[k]; v.z = szv[k];
    v.w = __uint_as_float((unsigned)orig);
    X4[dst] = v;
    if (orig == 0) *sid0p = dst;
  }
  __syncthreads();
  // ---- dump sorted cloud to global scratch (for k_radius) ----
  for (int e = tid; e < NPER; e += FPS_T) {
    float4 v = X4[e];
    gSX[e] = v.x; gSY[e] = v.y; gSZ[e] = v.z;
  }
  for (int e = tid; e < NPER/2; e += FPS_T) {
    unsigned o0 = __float_as_uint(X4[2*e].w) & 0xFFFFu;
    unsigned o1 = __float_as_uint(X4[2*e+1].w) & 0xFFFFu;
    gSO[e] = o0 | (o1 << 16);
  }
  // ---- own 8 contiguous sorted points + AABB ----
  v2f Xp[4], Yp[4], Zp[4], Dp[4];
  unsigned RK[PTS];
  float bxlo = 3.402823466e+38f, bylo = bxlo, bzlo = bxlo;
  float bxhi = -bxlo, byhi = bxhi, bzhi = bxhi;
#pragma unroll
  for (int k = 0; k < PTS; ++k) {
    int s = tid * PTS + k;
    float4 v = X4[s];
    Xp[k>>1][k&1] = v.x; Yp[k>>1][k&1] = v.y; Zp[k>>1][k&1] = v.z;
    Dp[k>>1][k&1] = 3.402823466e+38f;
    unsigned orig = __float_as_uint(v.w);
    RK[k] = ((unsigned)(NPER - 1 - orig) << 13) | (unsigned)s;
    bxlo = fminf(bxlo, v.x); bxhi = fmaxf(bxhi, v.x);
    bylo = fminf(bylo, v.y); byhi = fmaxf(byhi, v.y);
    bzlo = fminf(bzlo, v.z); bzhi = fmaxf(bzhi, v.z);
  }

  // ---- main loop ----
  unsigned long long tkey = 0ull, wkey = 0ull;
  float lmax = 3.402823466e+38f;
  unsigned sidx = *sid0p;
  for (int m = 1; m < MPER; ++m) {
    const float4 c4 = X4[sidx];         // one b128 broadcast
    const float cx = c4.x, cy = c4.y, cz = c4.z;
    if (tid == 0) winb[m-1] = (unsigned short)sidx;
    if (tid >= 4 && tid < 8)            // phase-safe future reset
      slot12[((m+1) % 3)*4 + (tid-4)] = 0ull;
    float ax = fmaxf(fmaxf(__fsub_rn(bxlo, cx), __fsub_rn(cx, bxhi)), 0.0f);
    float ay = fmaxf(fmaxf(__fsub_rn(bylo, cy), __fsub_rn(cy, byhi)), 0.0f);
    float az = fmaxf(fmaxf(__fsub_rn(bzlo, cz), __fsub_rn(cz, bzhi)), 0.0f);
    float lb = ax*ax + ay*ay + az*az;
    bool upd = (lb * 0.99988f) < lmax;  // margin >> rounding: skip is exact
    if (__ballot(upd) != 0ull) {        // whole wave can skip
      if (upd) {
        v2f cx2 = {cx, cx}, cy2 = {cy, cy}, cz2 = {cz, cz};
        v2f dnp[4];
        float bd = -1.0f;
#pragma unroll
        for (int p = 0; p < 4; ++p) {
          v2f dx = Xp[p] - cx2;
          v2f dy = Yp[p] - cy2;
          v2f dz = Zp[p] - cz2;
          v2f s = (dx*dx + dy*dy) + dz*dz;   // rn, no fma (contract off)
          v2f dn;
          dn.x = fminf(Dp[p].x, s.x);
          dn.y = fminf(Dp[p].y, s.y);
          Dp[p] = dn; dnp[p] = dn;
          bd = fmaxf(bd, fmaxf(dn.x, dn.y));
        }
        unsigned brk = 0u;
#pragma unroll
        for (int p = 0; p < 4; ++p) {
          brk = (dnp[p].x == bd) ? max(brk, RK[2*p])   : brk;
          brk = (dnp[p].y == bd) ? max(brk, RK[2*p+1]) : brk;
        }
        tkey = ((unsigned long long)__float_as_uint(bd) << 26) | brk;
        lmax = bd;
      }
      unsigned hi = (unsigned)(tkey >> 26);
      unsigned M = wave_max_u32(hi);
      unsigned rk = (unsigned)tkey & 0x3FFFFFFu;
      unsigned long long msk = __ballot(hi == M);
      unsigned lo;
      if (__popcll(msk) == 1) {          // sole owner (the ~always case)
        int ln = (int)__builtin_ctzll(msk);
        lo = (unsigned)__builtin_amdgcn_readlane((int)rk, ln);
      } else {                           // exact d2 tie: max RK = min orig
        lo = wave_max_u32((hi == M) ? rk : 0u);
      }
      wkey = ((unsigned long long)M << 26) | lo;
    }
    const int ph = (m % 3) * 4;
    if ((tid & 63) == 0) atomicMax(&slot12[ph + (wv & 3)], wkey);
    __syncthreads();
    unsigned long long k0 = slot12[ph+0], k1 = slot12[ph+1];
    unsigned long long k2 = slot12[ph+2], k3 = slot12[ph+3];
    k0 = (k1 > k0) ? k1 : k0;
    k2 = (k3 > k2) ? k3 : k2;
    k0 = (k2 > k0) ? k2 : k0;
    sidx = (unsigned)(k0 & 0x1FFFull);
  }
  if (tid == 0) winb[MPER-1] = (unsigned short)sidx;
  __syncthreads();
  // reconstruct pos_out from LDS
  for (int e = tid; e < MPER; e += FPS_T) {
    float4 v = X4[winb[e]];
    qo[e*3+0] = v.x; qo[e*3+1] = v.y; qo[e*3+2] = v.z;
  }
}

// ------------------------------------------------- K2: radius + top-K select
// One wave per centroid, cell-culled (+-2 cells, exact since R=0.2<2*0.125).
// 25 (ix,iy) segments of contiguous iz-runs; bounds prefetched lane-parallel.
// Candidates via ballot-prefix; (H=d2,L=orig) 512-bitonic -> bitwise-equal
// selection + lower-index tie-break to jax top_k.
#define SCAP 512
__global__ __launch_bounds__(256) void k_radius(const float* __restrict__ pos,
    float* __restrict__ dout, unsigned short* __restrict__ nbr,
    int* __restrict__ cnt)
{
  __shared__ unsigned candH[4][SCAP];
  __shared__ unsigned candL[4][SCAP];
  const int wid = threadIdx.x >> 6, lane = threadIdx.x & 63;
  const int m = blockIdx.x * 4 + wid;
  const int b = m >> 12;
  const float* scrb = dout + (size_t)b * SSTR;
  const float* SX = scrb;
  const float* SY = scrb + 8192;
  const float* SZ = scrb + 16384;
  const unsigned short* SO = (const unsigned short*)(scrb + 24576);
  const unsigned* CS = (const unsigned*)(scrb + 28672);
  const float* q = dout + POSOUT_OFF + (size_t)m * 3;
  const float qx = q[0], qy = q[1], qz = q[2];
  const int ixc = min(7, (int)(qx * 8.0f));
  const int iyc = min(7, (int)(qy * 8.0f));
  const int izc = min(7, (int)(qz * 8.0f));
  const int izlo = max(izc-2, 0), izhi = min(izc+2, 7);
  unsigned s0v = 0u, s1v = 0u;
  {
    int ix = ixc + lane / 5 - 2;
    int iy = iyc + lane % 5 - 2;
    if (lane < 25 && ix >= 0 && ix < 8 && iy >= 0 && iy < 8) {
      int cb = (ix << 6) | (iy << 3);
      s0v = CS[cb + izlo];
      s1v = CS[cb + izhi + 1];
    }
  }
  unsigned cw = 0;
  for (int seg = 0; seg < 25; ++seg) {
    unsigned s0 = (unsigned)__builtin_amdgcn_readlane((int)s0v, seg);
    unsigned s1 = (unsigned)__builtin_amdgcn_readlane((int)s1v, seg);
    for (unsigned i0 = s0; i0 < s1; i0 += 64) {
      unsigned i = i0 + (unsigned)lane;     // OOB lanes read harmless bytes
      float dx = __fsub_rn(qx, SX[i]);
      float dy = __fsub_rn(qy, SY[i]);
      float dz = __fsub_rn(qz, SZ[i]);
      float d2 = __fadd_rn(__fadd_rn(__fmul_rn(dx,dx), __fmul_rn(dy,dy)),
                           __fmul_rn(dz,dz));
      bool in = (i < s1) && (d2 <= R2C);
      unsigned long long mk = __ballot(in);
      unsigned pre = (unsigned)__popcll(mk & ((1ull << lane) - 1ull));
      if (in) {
        unsigned slot = cw + pre;
        if (slot < SCAP) {
          candH[wid][slot] = __float_as_uint(d2);
          candL[wid][slot] = (unsigned)SO[i];
        }
      }
      cw += (unsigned)__popcll(mk);
    }
  }
  if (cw > SCAP) cw = SCAP;
  for (int s = (int)cw + lane; s < SCAP; s += 64) {
    candH[wid][s] = 0xFFFFFFFFu; candL[wid][s] = 0xFFFFFFFFu;
  }
  __syncthreads();
  for (int k = 2; k <= SCAP; k <<= 1) {
    for (int j = k >> 1; j > 0; j >>= 1) {
#pragma unroll
      for (int s = 0; s < SCAP/128; ++s) {
        int t = lane + (s << 6);
        int e = ((t & ~(j-1)) << 1) | (t & (j-1));
        int p = e | j;
        unsigned aH = candH[wid][e], aL = candL[wid][e];
        unsigned cH = candH[wid][p], cL = candL[wid][p];
        bool agt = (aH > cH) || (aH == cH && aL > cL);
        bool asc = ((e & k) == 0);
        bool sw = asc ? agt : !agt && (aH != cH || aL != cL);
        if (sw) {
          candH[wid][e] = cH; candL[wid][e] = cL;
          candH[wid][p] = aH; candL[wid][p] = aL;
        }
      }
      __syncthreads();
    }
  }
  int kk = (int)cw; if (kk > KNB) kk = KNB;
  nbr[(size_t)m*KNB + lane] =
    (lane < kk) ? (unsigned short)(candL[wid][lane] & 0xFFFFu)
                : (unsigned short)0;
  if (lane == 0) {
    cnt[m] = kk;
    dout[BATCH_OFF + m] = (float)b;   // batch_out (buffer read as f32)
  }
}

// ------------------------------------------- K_pre: hp = x @ W1[:64] (once)
// 32768x64x64 GEMM; per-element fmaf k=0..63 sequential == conv's old ch
// order -> bitwise-identical partial sums. 512 blocks x 256 thr; 64-row
// tiles; thread = 4 rows x 4 cols.
__global__ __launch_bounds__(256) void k_pre(const float* __restrict__ x,
    const float* __restrict__ W1, float* __restrict__ hp)
{
  __shared__ float Ws[64*64];          // W1 rows 0..63 (ch-major [ch][h])
  __shared__ float Xs[64][65];
  const int t = threadIdx.x;
  const int row0 = blockIdx.x * 64;
  for (int e = t; e < 64*64; e += 256) Ws[e] = W1[e];
  for (int e = t; e < 64*64; e += 256) {
    int r = e >> 6, ch = e & 63;
    Xs[r][ch] = x[(size_t)(row0 + r) * 64 + ch];
  }
  __syncthreads();
  const int rg = t >> 4, cg = t & 15;
  const int r0 = rg << 2, c0 = cg << 2;
  float acc[4][4];
#pragma unroll
  for (int r = 0; r < 4; ++r)
#pragma unroll
    for (int c = 0; c < 4; ++c) acc[r][c] = 0.0f;
  for (int k = 0; k < 64; ++k) {
    const float4 w = *(const float4*)&Ws[(k << 6) + c0];
    const float xr[4] = {Xs[r0][k], Xs[r0+1][k], Xs[r0+2][k], Xs[r0+3][k]};
    const float wc[4] = {w.x, w.y, w.z, w.w};
#pragma unroll
    for (int r = 0; r < 4; ++r)
#pragma unroll
      for (int c = 0; c < 4; ++c)
        acc[r][c] = fmaf(xr[r], wc[c], acc[r][c]);
  }
#pragma unroll
  for (int r = 0; r < 4; ++r) {
    float4 o = {acc[r][0], acc[r][1], acc[r][2], acc[r][3]};
    *(float4*)&hp[(size_t)(row0 + r0 + r) * 64 + c0] = o;
  }
}

// ---------------------------------- K3a: conv using precomp (ws-size gated)
// Gather hp rows (h1 partial sums) -> h1T in LDS; fuse rel@W1[64:67] + b1 +
// relu (fmaf order 64,65,66 then +b1: bitwise == legacy); stage2 packed
// v_pk_fma as before. LDS ~28KB -> 5 blocks/CU.
__global__ __launch_bounds__(128) void k_conv2(
    const float* __restrict__ hp, const float* __restrict__ pos,
    const float* __restrict__ W1, const float* __restrict__ b1,
    const float* __restrict__ W2, const float* __restrict__ b2,
    const unsigned short* __restrict__ nbr, const int* __restrict__ cntp,
    float* __restrict__ dout)
{
  __shared__ __align__(16) float bufA[68*68];   // h1T rows 0..63, relT 64..66
  __shared__ __align__(16) float bufB[16*136];  // W2 chunk (stride 136)
  __shared__ float w1p[3*64];
  __shared__ unsigned short nbr_s[64];
  __shared__ float qv[3];
  __shared__ int cnt_s;
  const int t = threadIdx.x;
  const int m = blockIdx.x;
  const int b = m >> 12;
  if (t < 64) nbr_s[t] = nbr[(size_t)m*KNB + t];
  else if (t == 64) cnt_s = cntp[m];
  else if (t >= 65 && t < 68) qv[t-65] = dout[POSOUT_OFF + (size_t)m*3 + (t-65)];
  for (int e = t; e < 192; e += 128) w1p[e] = W1[64*64 + e];
  __syncthreads();
  {                                   // gather hp rows -> h1T rows 0..63
    const int h = t & 63, jj = t >> 6;
    const size_t hb = (size_t)b * NPER * 64;
    for (int j0 = 0; j0 < 64; j0 += 2) {
      int j = j0 + jj;
      int r = nbr_s[j];
      bufA[h*68 + j] = hp[hb + (size_t)r*64 + h];
    }
  }
  {                                   // rel -> rows 64..66
    const size_t pbb = (size_t)b * NPER * 3;
    for (int e = t; e < 192; e += 128) {
      int j = e & 63, d = e >> 6;
      int r = nbr_s[j];
      bufA[(64+d)*68 + j] = pos[pbb + (size_t)r*3 + d] - qv[d];
    }
  }
  __syncthreads();
  // fuse: h1T[h][j] = relu(h1T + rel@w1p + b1)  (fmaf order 64,65,66, +b1)
  for (int e = t; e < 64*64; e += 128) {
    int h = e >> 6, j = e & 63;
    float v = bufA[h*68 + j];
    v = fmaf(bufA[64*68 + j], w1p[h],       v);
    v = fmaf(bufA[65*68 + j], w1p[64 + h],  v);
    v = fmaf(bufA[66*68 + j], w1p[128 + h], v);
    bufA[h*68 + j] = fmaxf(v + b1[h], 0.0f);
  }
  const int jg = t & 7, hg = t >> 3;
  const int j0 = jg << 3;
  const int c0 = hg << 3;             // stage2: 8j x 8c packed pairs
  v2f acc2p[8][4];                    // [c][jpair]
#pragma unroll
  for (int c = 0; c < 8; ++c)
#pragma unroll
    for (int jp = 0; jp < 4; ++jp) acc2p[c][jp] = (v2f){0.0f, 0.0f};
  for (int hc = 0; hc < 64; hc += 16) {
    __syncthreads();                  // h1T ready / prior chunk consumed
    for (int e = t; e < 16*128; e += 128) {
      int hh = e >> 7, c = e & 127;
      bufB[hh*136 + c] = W2[(size_t)(hc+hh)*128 + c];
    }
    __syncthreads();
#pragma unroll
    for (int h = 0; h < 16; ++h) {
      const float4 ja = *(const float4*)&bufA[(hc+h)*68 + j0];
      const float4 jb = *(const float4*)&bufA[(hc+h)*68 + j0 + 4];
      const float4 wa = *(const float4*)&bufB[h*136 + c0];
      const float4 wb = *(const float4*)&bufB[h*136 + c0 + 4];
      const v2f hj[4] = {{ja.x, ja.y}, {ja.z, ja.w}, {jb.x, jb.y}, {jb.z, jb.w}};
      const float wv[8] = {wa.x, wa.y, wa.z, wa.w, wb.x, wb.y, wb.z, wb.w};
#pragma unroll
      for (int c = 0; c < 8; ++c) {
        const v2f w2 = {wv[c], wv[c]};
#pragma unroll
        for (int jp = 0; jp < 4; ++jp)
          acc2p[c][jp] += w2 * hj[jp];          // v_pk_fma_f32
      }
    }
  }
  const int cntv = cnt_s;
  const float4 b2a = *(const float4*)&b2[c0];
  const float4 b2b = *(const float4*)&b2[c0 + 4];
  const float bv2[8] = {b2a.x, b2a.y, b2a.z, b2a.w, b2b.x, b2b.y, b2b.z, b2b.w};
  float best[8];
#pragma unroll
  for (int c = 0; c < 8; ++c) {
    float v = -3.402823466e+38f;
#pragma unroll
    for (int jp = 0; jp < 4; ++jp) {
      float h0v = fmaxf(acc2p[c][jp].x + bv2[c], 0.0f);
      float h1v = fmaxf(acc2p[c][jp].y + bv2[c], 0.0f);
      v = (j0 + 2*jp     < cntv) ? fmaxf(v, h0v) : v;
      v = (j0 + 2*jp + 1 < cntv) ? fmaxf(v, h1v) : v;
    }
    best[c] = v;
  }
#pragma unroll
  for (int off = 1; off < 8; off <<= 1)
#pragma unroll
    for (int c = 0; c < 8; ++c)
      best[c] = fmaxf(best[c], __shfl_xor(best[c], off));
  if (jg == 0) {
    float4 o0 = {best[0], best[1], best[2], best[3]};
    float4 o1 = {best[4], best[5], best[6], best[7]};
    *(float4*)&dout[(size_t)m*128 + c0] = o0;
    *(float4*)&dout[(size_t)m*128 + c0 + 4] = o1;
  }
}

// --------------------------------------------- K3b: legacy conv (fallback)
__global__ __launch_bounds__(128) void k_conv(
    const float* __restrict__ x, const float* __restrict__ pos,
    const float* __restrict__ W1, const float* __restrict__ b1,
    const float* __restrict__ W2, const float* __restrict__ b2,
    const unsigned short* __restrict__ nbr, const int* __restrict__ cntp,
    float* __restrict__ dout)
{
  __shared__ __align__(16) float bufA[68*68];
  __shared__ __align__(16) float bufB[68*68];
  __shared__ unsigned short nbr_s[64];
  __shared__ float qv[3];
  __shared__ int cnt_s;
  const int t = threadIdx.x;
  const int m = blockIdx.x;
  const int b = m >> 12;
  if (t < 64) nbr_s[t] = nbr[(size_t)m*KNB + t];
  else if (t == 64) cnt_s = cntp[m];
  else if (t >= 65 && t < 68) qv[t-65] = dout[POSOUT_OFF + (size_t)m*3 + (t-65)];
  for (int e = t; e < 67*64; e += 128) {
    int ch = e >> 6, h = e & 63;
    bufB[ch*68 + h] = W1[e];
  }
  __syncthreads();
  {
    const int ch = t & 63, jj = t >> 6;
    const size_t xb = (size_t)b * NPER * CIN;
    for (int j0 = 0; j0 < 64; j0 += 2) {
      int j = j0 + jj;
      int r = nbr_s[j];
      bufA[ch*68 + j] = x[xb + (size_t)r*CIN + ch];
    }
  }
  {
    const size_t pbb = (size_t)b * NPER * 3;
    for (int e = t; e < 192; e += 128) {
      int j = e & 63, d = e >> 6;
      int r = nbr_s[j];
      bufA[(64+d)*68 + j] = pos[pbb + (size_t)r*3 + d] - qv[d];
    }
  }
  __syncthreads();
  const int jg = t & 7, hg = t >> 3;
  const int j0 = jg << 3;
  const int h0 = hg << 2;
  v2f accp[4][4];
#pragma unroll
  for (int hh = 0; hh < 4; ++hh)
#pragma unroll
    for (int jp = 0; jp < 4; ++jp) accp[hh][jp] = (v2f){0.0f, 0.0f};
  for (int ch = 0; ch < 67; ++ch) {
    const float4 fa = *(const float4*)&bufA[ch*68 + j0];
    const float4 fb = *(const float4*)&bufA[ch*68 + j0 + 4];
    const float4 w  = *(const float4*)&bufB[ch*68 + h0];
    const v2f fj[4] = {{fa.x, fa.y}, {fa.z, fa.w}, {fb.x, fb.y}, {fb.z, fb.w}};
    const float ws4[4] = {w.x, w.y, w.z, w.w};
#pragma unroll
    for (int hh = 0; hh < 4; ++hh) {
      const v2f wv2 = {ws4[hh], ws4[hh]};
#pragma unroll
      for (int jp = 0; jp < 4; ++jp)
        accp[hh][jp] += wv2 * fj[jp];
    }
  }
  __syncthreads();
  {
    const float4 bb = *(const float4*)&b1[h0];
    const float bv[4] = {bb.x, bb.y, bb.z, bb.w};
#pragma unroll
    for (int hh = 0; hh < 4; ++hh) {
      float4 o0, o1;
      o0.x = fmaxf(accp[hh][0].x + bv[hh], 0.0f);
      o0.y = fmaxf(accp[hh][0].y + bv[hh], 0.0f);
      o0.z = fmaxf(accp[hh][1].x + bv[hh], 0.0f);
      o0.w = fmaxf(accp[hh][1].y + bv[hh], 0.0f);
      o1.x = fmaxf(accp[hh][2].x + bv[hh], 0.0f);
      o1.y = fmaxf(accp[hh][2].y + bv[hh], 0.0f);
      o1.z = fmaxf(accp[hh][3].x + bv[hh], 0.0f);
      o1.w = fmaxf(accp[hh][3].y + bv[hh], 0.0f);
      *(float4*)&bufA[(h0+hh)*68 + j0] = o0;
      *(float4*)&bufA[(h0+hh)*68 + j0 + 4] = o1;
    }
  }
  const int c0 = hg << 3;
  v2f acc2p[8][4];
#pragma unroll
  for (int c = 0; c < 8; ++c)
#pragma unroll
    for (int jp = 0; jp < 4; ++jp) acc2p[c][jp] = (v2f){0.0f, 0.0f};
  for (int hc = 0; hc < 64; hc += 16) {
    __syncthreads();
    for (int e = t; e < 16*128; e += 128) {
      int hh = e >> 7, c = e & 127;
      bufB[hh*136 + c] = W2[(size_t)(hc+hh)*128 + c];
    }
    __syncthreads();
#pragma unroll
    for (int h = 0; h < 16; ++h) {
      const float4 ja = *(const float4*)&bufA[(hc+h)*68 + j0];
      const float4 jb = *(const float4*)&bufA[(hc+h)*68 + j0 + 4];
      const float4 wa = *(const float4*)&bufB[h*136 + c0];
      const float4 wb = *(const float4*)&bufB[h*136 + c0 + 4];
      const v2f hj[4] = {{ja.x, ja.y}, {ja.z, ja.w}, {jb.x, jb.y}, {jb.z, jb.w}};
      const float wv[8] = {wa.x, wa.y, wa.z, wa.w, wb.x, wb.y, wb.z, wb.w};
#pragma unroll
      for (int c = 0; c < 8; ++c) {
        const v2f w2 = {wv[c], wv[c]};
#pragma unroll
        for (int jp = 0; jp < 4; ++jp)
          acc2p[c][jp] += w2 * hj[jp];
      }
    }
  }
  const int cntv = cnt_s;
  const float4 b2a = *(const float4*)&b2[c0];
  const float4 b2b = *(const float4*)&b2[c0 + 4];
  const float bv2[8] = {b2a.x, b2a.y, b2a.z, b2a.w, b2b.x, b2b.y, b2b.z, b2b.w};
  float best[8];
#pragma unroll
  for (int c = 0; c < 8; ++c) {
    float v = -3.402823466e+38f;
#pragma unroll
    for (int jp = 0; jp < 4; ++jp) {
      float h0v = fmaxf(acc2p[c][jp].x + bv2[c], 0.0f);
      float h1v = fmaxf(acc2p[c][jp].y + bv2[c], 0.0f);
      v = (j0 + 2*jp     < cntv) ? fmaxf(v, h0v) : v;
      v = (j0 + 2*jp + 1 < cntv) ? fmaxf(v, h1v) : v;
    }
    best[c] = v;
  }
#pragma unroll
  for (int off = 1; off < 8; off <<= 1)
#pragma unroll
    for (int c = 0; c < 8; ++c)
      best[c] = fmaxf(best[c], __shfl_xor(best[c], off));
  if (jg == 0) {
    float4 o0 = {best[0], best[1], best[2], best[3]};
    float4 o1 = {best[4], best[5], best[6], best[7]};
    *(float4*)&dout[(size_t)m*128 + c0] = o0;
    *(float4*)&dout[(size_t)m*128 + c0 + 4] = o1;
  }
}

extern "C" void kernel_launch(void* const* d_in, const int* in_sizes, int n_in,
                              void* d_out, int out_size, void* d_ws, size_t ws_size,
                              hipStream_t stream) {
  const float* x   = (const float*)d_in[0];
  const float* pos = (const float*)d_in[1];
  // d_in[2] = batch (layout known statically, unused)
  const float* W1  = (const float*)d_in[3];
  const float* b1  = (const float*)d_in[4];
  const float* W2  = (const float*)d_in[5];
  const float* b2  = (const float*)d_in[6];
  float* dout = (float*)d_out;
  unsigned short* nbr = (unsigned short*)d_ws;
  int* cnt = (int*)((char*)d_ws + (size_t)MTOT*KNB*2);
  float* hp = (float*)((char*)d_ws + PRE_OFF);
  const bool use_pre = (ws_size >= PRE_OFF + PRE_BYTES);  // constant per run

  hipLaunchKernelGGL(k_fps,    dim3(NB),     dim3(FPS_T), FPS_LDS, stream, pos, dout);
  hipLaunchKernelGGL(k_radius, dim3(MTOT/4), dim3(256),   0, stream, pos, dout, nbr, cnt);
  if (use_pre) {
    hipLaunchKernelGGL(k_pre,   dim3(NB*NPER/64), dim3(256), 0, stream, x, W1, hp);
    hipLaunchKernelGGL(k_conv2, dim3(MTOT),       dim3(128), 0, stream,
                       hp, pos, W1, b1, W2, b2, nbr, cnt, dout);
  } else {
    hipLaunchKernelGGL(k_conv,  dim3(MTOT),       dim3(128), 0, stream,
                       x, pos, W1, b1, W2, b2, nbr, cnt, dout);
  }
}

// Round 12
// 3012.704 us; speedup vs baseline: 1.0934x; 1.0934x over previous
//
#include <hip/hip_runtime.h>
#include <stdint.h>

#define NPER 8192
#define NB 4
#define MPER 4096
#define MTOT (NB*MPER)      // 16384
#define KNB 64
#define CIN 64
#define R2C 0.04f           // f32-nearest of python 0.2*0.2 (NOT 0.2f*0.2f!)

// d_out (floats): x_out [MTOT*128] | pos_out [MTOT*3] | batch_out [MTOT]
#define POSOUT_OFF (MTOT*128)
#define BATCH_OFF  (MTOT*128 + MTOT*3)

// ws: nbr u16 [MTOT*64] @0 (2MB) | cnt i32 [MTOT] @2MB (64KB) |
//     precomp f32[32768*64] @PRE_OFF (8MB, optional: ws_size-gated)
#define PRE_OFF 2162688ull
#define PRE_BYTES 8388608ull

// fps->radius scratch in x_out region of d_out (free until k_conv):
// per cloud stride SSTR floats: SX[8192] @0 | SY @8192 | SZ @16384 |
// SO u16[8192] @24576f | CS u32[513] @28672f   (sorted by lex cell)
#define SSTR 30720

typedef float v2f __attribute__((ext_vector_type(2)));

// ---------------------------------------------------------------- K1: FPS
// R10-proven exact lazy FPS (2518 us) — restored verbatim after R11's
// "tail optimizations" (float4 LDS + 4-slot reduce) regressed +250us:
// post-barrier multi-slot reduce is serial latency, while the 16-wave
// same-address atomicMax overlaps with barrier wait. Do not touch this
// loop shape (R5/R9/R11 all regressed it).
// 1024 thr, 8 pts/thread lex-cell-sorted, AABB prune w/ fresh lmax
// (provably-exact skip: 1.2e-4 margin >> 5e-7 f32 rounding), bitwise-numpy
// update ((dx*dx+dy*dy)+dz*dz, rn, no fma), key=(bd<<26)|brk (max d2,
// tie -> min orig = np.argmax first-max), DPP wave max + single-owner
// readlane, per-wave LDS atomicMax into 3-phase slot, ONE barrier/iter.
#define FPS_T 1024
#define PTS 8
#define NCELL 512

// dynamic-LDS layout (bytes)
#define OFF_XS 0
#define OFF_YS (OFF_XS + NPER*4)        // 32768
#define OFF_ZS (OFF_YS + NPER*4)        // 65536
#define OFF_OS (OFF_ZS + NPER*4)        // 98304  u16[8192]
#define OFF_WIN (OFF_OS + NPER*2)       // 114688 u16[4096]
#define OFF_HIST (OFF_WIN + MPER*2)     // 122880 u32[512]
#define OFF_SCAN (OFF_HIST + NCELL*4)   // 124928 u32[512]
#define OFF_SLOT (OFF_SCAN + NCELL*4)   // 126976 u64[3]
#define OFF_SID0 (OFF_SLOT + 24)        // 127000 u32
#define FPS_LDS  (OFF_SID0 + 8)         // 127008 B

template<int CTRL>
__device__ __forceinline__ unsigned dppmax(unsigned v) {
  unsigned t = (unsigned)__builtin_amdgcn_update_dpp(
      0, (int)v, CTRL, 0xf, 0xf, true);   // bound_ctrl: OOB lanes read 0
  return v > t ? v : t;
}
__device__ __forceinline__ unsigned wave_max_u32(unsigned v) {
  v = dppmax<0x111>(v);   // row_shr:1
  v = dppmax<0x112>(v);   // row_shr:2
  v = dppmax<0x114>(v);   // row_shr:4
  v = dppmax<0x118>(v);   // row_shr:8
  v = dppmax<0x142>(v);   // row_bcast15
  v = dppmax<0x143>(v);   // row_bcast31
  return (unsigned)__builtin_amdgcn_readlane((int)v, 63);
}

__global__ __launch_bounds__(1024) void k_fps(const float* __restrict__ pos,
                                              float* __restrict__ dout)
{
#pragma clang fp contract(off)
  extern __shared__ char smem[];
  float* Xs = (float*)(smem + OFF_XS);
  float* Ys = (float*)(smem + OFF_YS);
  float* Zs = (float*)(smem + OFF_ZS);
  unsigned short* Os = (unsigned short*)(smem + OFF_OS);
  unsigned short* winb = (unsigned short*)(smem + OFF_WIN);
  unsigned* hist = (unsigned*)(smem + OFF_HIST);
  unsigned* scanb = (unsigned*)(smem + OFF_SCAN);
  unsigned long long* slot3 = (unsigned long long*)(smem + OFF_SLOT);
  unsigned* sid0p = (unsigned*)(smem + OFF_SID0);

  const int b = blockIdx.x;
  const int tid = threadIdx.x;
  const float* pb = pos + (size_t)b * NPER * 3;
  float* qo = dout + POSOUT_OFF + (size_t)b * MPER * 3;
  float* scrb = dout + (size_t)b * SSTR;
  float* gSX = scrb; float* gSY = scrb + 8192; float* gSZ = scrb + 16384;
  unsigned* gSO = (unsigned*)(scrb + 24576);       // packed u16 pairs
  unsigned* gCS = (unsigned*)(scrb + 28672);       // 513 entries

  if (tid < NCELL) hist[tid] = 0u;
  if (tid == 0) { slot3[0] = 0ull; slot3[1] = 0ull; slot3[2] = 0ull; }
  __syncthreads();

  // ---- sort pass 1: count (lex cell) ----
  float sxv[PTS], syv[PTS], szv[PTS];
  unsigned cellv[PTS];
#pragma unroll
  for (int k = 0; k < PTS; ++k) {
    int i = k * FPS_T + tid;
    sxv[k] = pb[i*3+0]; syv[k] = pb[i*3+1]; szv[k] = pb[i*3+2];
    unsigned ix = min(7u, (unsigned)(int)(sxv[k] * 8.0f));
    unsigned iy = min(7u, (unsigned)(int)(syv[k] * 8.0f));
    unsigned iz = min(7u, (unsigned)(int)(szv[k] * 8.0f));
    cellv[k] = (ix << 6) | (iy << 3) | iz;
    atomicAdd(&hist[cellv[k]], 1u);
  }
  __syncthreads();
  // ---- scan -> exclusive starts; export CS to global ----
  if (tid < NCELL) scanb[tid] = hist[tid];
  __syncthreads();
  for (int s = 1; s < NCELL; s <<= 1) {
    unsigned v = 0u;
    if (tid >= s && tid < NCELL) v = scanb[tid - s];
    __syncthreads();
    if (tid >= s && tid < NCELL) scanb[tid] += v;
    __syncthreads();
  }
  if (tid < NCELL) {
    hist[tid] = scanb[tid] - hist[tid];   // exclusive start
    gCS[tid+1] = scanb[tid];              // start of cell tid+1
  }
  if (tid == 0) gCS[0] = 0u;
  __syncthreads();
  // ---- sort pass 2: scatter into LDS ----
#pragma unroll
  for (int k = 0; k < PTS; ++k) {
    unsigned dst = atomicAdd(&hist[cellv[k]], 1u);
    int orig = k * FPS_T + tid;
    Xs[dst] = sxv[k]; Ys[dst] = syv[k]; Zs[dst] = szv[k];
    Os[dst] = (unsigned short)orig;
    if (orig == 0) *sid0p = dst;
  }
  __syncthreads();
  // ---- dump sorted cloud to global scratch (for k_radius) ----
  for (int e = tid; e < NPER; e += FPS_T) {
    gSX[e] = Xs[e]; gSY[e] = Ys[e]; gSZ[e] = Zs[e];
  }
  for (int e = tid; e < NPER/2; e += FPS_T)
    gSO[e] = ((const unsigned*)Os)[e];
  // ---- own 8 contiguous sorted points + AABB ----
  v2f Xp[4], Yp[4], Zp[4], Dp[4];
  unsigned RK[PTS];
  float bxlo = 3.402823466e+38f, bylo = bxlo, bzlo = bxlo;
  float bxhi = -bxlo, byhi = bxhi, bzhi = bxhi;
#pragma unroll
  for (int k = 0; k < PTS; ++k) {
    int s = tid * PTS + k;
    float xx = Xs[s], yy = Ys[s], zz = Zs[s];
    Xp[k>>1][k&1] = xx; Yp[k>>1][k&1] = yy; Zp[k>>1][k&1] = zz;
    Dp[k>>1][k&1] = 3.402823466e+38f;
    unsigned orig = Os[s];
    RK[k] = ((unsigned)(NPER - 1 - orig) << 13) | (unsigned)s;
    bxlo = fminf(bxlo, xx); bxhi = fmaxf(bxhi, xx);
    bylo = fminf(bylo, yy); byhi = fmaxf(byhi, yy);
    bzlo = fminf(bzlo, zz); bzhi = fmaxf(bzhi, zz);
  }

  // ---- main loop ----
  unsigned long long tkey = 0ull, wkey = 0ull;
  float lmax = 3.402823466e+38f;
  unsigned sidx = *sid0p;
  for (int m = 1; m < MPER; ++m) {
    const float cx = Xs[sidx], cy = Ys[sidx], cz = Zs[sidx];  // broadcasts
    if (tid == 0) winb[m-1] = (unsigned short)sidx;
    if (tid == 1) slot3[(m+1) % 3] = 0ull;   // phase-safe future reset
    float ax = fmaxf(fmaxf(__fsub_rn(bxlo, cx), __fsub_rn(cx, bxhi)), 0.0f);
    float ay = fmaxf(fmaxf(__fsub_rn(bylo, cy), __fsub_rn(cy, byhi)), 0.0f);
    float az = fmaxf(fmaxf(__fsub_rn(bzlo, cz), __fsub_rn(cz, bzhi)), 0.0f);
    float lb = ax*ax + ay*ay + az*az;
    bool upd = (lb * 0.99988f) < lmax;  // margin >> rounding: skip is exact
    if (__ballot(upd) != 0ull) {        // whole wave can skip
      if (upd) {
        v2f cx2 = {cx, cx}, cy2 = {cy, cy}, cz2 = {cz, cz};
        v2f dnp[4];
        float bd = -1.0f;
#pragma unroll
        for (int p = 0; p < 4; ++p) {
          v2f dx = Xp[p] - cx2;
          v2f dy = Yp[p] - cy2;
          v2f dz = Zp[p] - cz2;
          v2f s = (dx*dx + dy*dy) + dz*dz;   // rn, no fma (contract off)
          v2f dn;
          dn.x = fminf(Dp[p].x, s.x);
          dn.y = fminf(Dp[p].y, s.y);
          Dp[p] = dn; dnp[p] = dn;
          bd = fmaxf(bd, fmaxf(dn.x, dn.y));
        }
        unsigned brk = 0u;
#pragma unroll
        for (int p = 0; p < 4; ++p) {
          brk = (dnp[p].x == bd) ? max(brk, RK[2*p])   : brk;
          brk = (dnp[p].y == bd) ? max(brk, RK[2*p+1]) : brk;
        }
        tkey = ((unsigned long long)__float_as_uint(bd) << 26) | brk;
        lmax = bd;
      }
      unsigned hi = (unsigned)(tkey >> 26);
      unsigned M = wave_max_u32(hi);
      unsigned rk = (unsigned)tkey & 0x3FFFFFFu;
      unsigned long long msk = __ballot(hi == M);
      unsigned lo;
      if (__popcll(msk) == 1) {          // sole owner (the ~always case)
        int ln = (int)__builtin_ctzll(msk);
        lo = (unsigned)__builtin_amdgcn_readlane((int)rk, ln);
      } else {                           // exact d2 tie: max RK = min orig
        lo = wave_max_u32((hi == M) ? rk : 0u);
      }
      wkey = ((unsigned long long)M << 26) | lo;
    }
    if ((tid & 63) == 0) atomicMax(&slot3[m % 3], wkey);
    __syncthreads();
    sidx = (unsigned)(slot3[m % 3] & 0x1FFFull);
  }
  if (tid == 0) winb[MPER-1] = (unsigned short)sidx;
  __syncthreads();
  // reconstruct pos_out from LDS
  for (int e = tid; e < MPER; e += FPS_T) {
    unsigned s = winb[e];
    qo[e*3+0] = Xs[s]; qo[e*3+1] = Ys[s]; qo[e*3+2] = Zs[s];
  }
}

// ------------------------------------------------- K2: radius + top-K select
// One wave per centroid, cell-culled (+-2 cells, exact since R=0.2<2*0.125).
// 25 (ix,iy) segments of contiguous iz-runs; bounds prefetched lane-parallel.
// Candidates via ballot-prefix; (H=d2,L=orig) 512-bitonic -> bitwise-equal
// selection + lower-index tie-break to jax top_k.
#define SCAP 512
__global__ __launch_bounds__(256) void k_radius(const float* __restrict__ pos,
    float* __restrict__ dout, unsigned short* __restrict__ nbr,
    int* __restrict__ cnt)
{
  __shared__ unsigned candH[4][SCAP];
  __shared__ unsigned candL[4][SCAP];
  const int wid = threadIdx.x >> 6, lane = threadIdx.x & 63;
  const int m = blockIdx.x * 4 + wid;
  const int b = m >> 12;
  const float* scrb = dout + (size_t)b * SSTR;
  const float* SX = scrb;
  const float* SY = scrb + 8192;
  const float* SZ = scrb + 16384;
  const unsigned short* SO = (const unsigned short*)(scrb + 24576);
  const unsigned* CS = (const unsigned*)(scrb + 28672);
  const float* q = dout + POSOUT_OFF + (size_t)m * 3;
  const float qx = q[0], qy = q[1], qz = q[2];
  const int ixc = min(7, (int)(qx * 8.0f));
  const int iyc = min(7, (int)(qy * 8.0f));
  const int izc = min(7, (int)(qz * 8.0f));
  const int izlo = max(izc-2, 0), izhi = min(izc+2, 7);
  unsigned s0v = 0u, s1v = 0u;
  {
    int ix = ixc + lane / 5 - 2;
    int iy = iyc + lane % 5 - 2;
    if (lane < 25 && ix >= 0 && ix < 8 && iy >= 0 && iy < 8) {
      int cb = (ix << 6) | (iy << 3);
      s0v = CS[cb + izlo];
      s1v = CS[cb + izhi + 1];
    }
  }
  unsigned cw = 0;
  for (int seg = 0; seg < 25; ++seg) {
    unsigned s0 = (unsigned)__builtin_amdgcn_readlane((int)s0v, seg);
    unsigned s1 = (unsigned)__builtin_amdgcn_readlane((int)s1v, seg);
    for (unsigned i0 = s0; i0 < s1; i0 += 64) {
      unsigned i = i0 + (unsigned)lane;     // OOB lanes read harmless bytes
      float dx = __fsub_rn(qx, SX[i]);
      float dy = __fsub_rn(qy, SY[i]);
      float dz = __fsub_rn(qz, SZ[i]);
      float d2 = __fadd_rn(__fadd_rn(__fmul_rn(dx,dx), __fmul_rn(dy,dy)),
                           __fmul_rn(dz,dz));
      bool in = (i < s1) && (d2 <= R2C);
      unsigned long long mk = __ballot(in);
      unsigned pre = (unsigned)__popcll(mk & ((1ull << lane) - 1ull));
      if (in) {
        unsigned slot = cw + pre;
        if (slot < SCAP) {
          candH[wid][slot] = __float_as_uint(d2);
          candL[wid][slot] = (unsigned)SO[i];
        }
      }
      cw += (unsigned)__popcll(mk);
    }
  }
  if (cw > SCAP) cw = SCAP;
  for (int s = (int)cw + lane; s < SCAP; s += 64) {
    candH[wid][s] = 0xFFFFFFFFu; candL[wid][s] = 0xFFFFFFFFu;
  }
  __syncthreads();
  for (int k = 2; k <= SCAP; k <<= 1) {
    for (int j = k >> 1; j > 0; j >>= 1) {
#pragma unroll
      for (int s = 0; s < SCAP/128; ++s) {
        int t = lane + (s << 6);
        int e = ((t & ~(j-1)) << 1) | (t & (j-1));
        int p = e | j;
        unsigned aH = candH[wid][e], aL = candL[wid][e];
        unsigned cH = candH[wid][p], cL = candL[wid][p];
        bool agt = (aH > cH) || (aH == cH && aL > cL);
        bool asc = ((e & k) == 0);
        bool sw = asc ? agt : !agt && (aH != cH || aL != cL);
        if (sw) {
          candH[wid][e] = cH; candL[wid][e] = cL;
          candH[wid][p] = aH; candL[wid][p] = aL;
        }
      }
      __syncthreads();
    }
  }
  int kk = (int)cw; if (kk > KNB) kk = KNB;
  nbr[(size_t)m*KNB + lane] =
    (lane < kk) ? (unsigned short)(candL[wid][lane] & 0xFFFFu)
                : (unsigned short)0;
  if (lane == 0) {
    cnt[m] = kk;
    dout[BATCH_OFF + m] = (float)b;   // batch_out (buffer read as f32)
  }
}

// ------------------------------------------- K_pre: hp = x @ W1[:64] (once)
// 32768x64x64 GEMM; per-element fmaf k=0..63 sequential == conv's old ch
// order -> bitwise-identical partial sums. 512 blocks x 256 thr.
__global__ __launch_bounds__(256) void k_pre(const float* __restrict__ x,
    const float* __restrict__ W1, float* __restrict__ hp)
{
  __shared__ float Ws[64*64];          // W1 rows 0..63 (ch-major [ch][h])
  __shared__ float Xs[64][65];
  const int t = threadIdx.x;
  const int row0 = blockIdx.x * 64;
  for (int e = t; e < 64*64; e += 256) Ws[e] = W1[e];
  for (int e = t; e < 64*64; e += 256) {
    int r = e >> 6, ch = e & 63;
    Xs[r][ch] = x[(size_t)(row0 + r) * 64 + ch];
  }
  __syncthreads();
  const int rg = t >> 4, cg = t & 15;
  const int r0 = rg << 2, c0 = cg << 2;
  float acc[4][4];
#pragma unroll
  for (int r = 0; r < 4; ++r)
#pragma unroll
    for (int c = 0; c < 4; ++c) acc[r][c] = 0.0f;
  for (int k = 0; k < 64; ++k) {
    const float4 w = *(const float4*)&Ws[(k << 6) + c0];
    const float xr[4] = {Xs[r0][k], Xs[r0+1][k], Xs[r0+2][k], Xs[r0+3][k]};
    const float wc[4] = {w.x, w.y, w.z, w.w};
#pragma unroll
    for (int r = 0; r < 4; ++r)
#pragma unroll
      for (int c = 0; c < 4; ++c)
        acc[r][c] = fmaf(xr[r], wc[c], acc[r][c]);
  }
#pragma unroll
  for (int r = 0; r < 4; ++r) {
    float4 o = {acc[r][0], acc[r][1], acc[r][2], acc[r][3]};
    *(float4*)&hp[(size_t)(row0 + r0 + r) * 64 + c0] = o;
  }
}

// ---------------------------------- K3a: conv using precomp (ws-size gated)
// Gather hp rows (h1 partial sums) -> h1T in LDS; fuse rel@W1[64:67] + b1 +
// relu (fmaf order 64,65,66 then +b1: bitwise == legacy); stage2 packed
// v_pk_fma. LDS ~28KB.
__global__ __launch_bounds__(128) void k_conv2(
    const float* __restrict__ hp, const float* __restrict__ pos,
    const float* __restrict__ W1, const float* __restrict__ b1,
    const float* __restrict__ W2, const float* __restrict__ b2,
    const unsigned short* __restrict__ nbr, const int* __restrict__ cntp,
    float* __restrict__ dout)
{
  __shared__ __align__(16) float bufA[68*68];   // h1T rows 0..63, relT 64..66
  __shared__ __align__(16) float bufB[16*136];  // W2 chunk (stride 136)
  __shared__ float w1p[3*64];
  __shared__ unsigned short nbr_s[64];
  __shared__ float qv[3];
  __shared__ int cnt_s;
  const int t = threadIdx.x;
  const int m = blockIdx.x;
  const int b = m >> 12;
  if (t < 64) nbr_s[t] = nbr[(size_t)m*KNB + t];
  else if (t == 64) cnt_s = cntp[m];
  else if (t >= 65 && t < 68) qv[t-65] = dout[POSOUT_OFF + (size_t)m*3 + (t-65)];
  for (int e = t; e < 192; e += 128) w1p[e] = W1[64*64 + e];
  __syncthreads();
  {                                   // gather hp rows -> h1T rows 0..63
    const int h = t & 63, jj = t >> 6;
    const size_t hb = (size_t)b * NPER * 64;
    for (int j0 = 0; j0 < 64; j0 += 2) {
      int j = j0 + jj;
      int r = nbr_s[j];
      bufA[h*68 + j] = hp[hb + (size_t)r*64 + h];
    }
  }
  {                                   // rel -> rows 64..66
    const size_t pbb = (size_t)b * NPER * 3;
    for (int e = t; e < 192; e += 128) {
      int j = e & 63, d = e >> 6;
      int r = nbr_s[j];
      bufA[(64+d)*68 + j] = pos[pbb + (size_t)r*3 + d] - qv[d];
    }
  }
  __syncthreads();
  // fuse: h1T[h][j] = relu(h1T + rel@w1p + b1)  (fmaf order 64,65,66, +b1)
  for (int e = t; e < 64*64; e += 128) {
    int h = e >> 6, j = e & 63;
    float v = bufA[h*68 + j];
    v = fmaf(bufA[64*68 + j], w1p[h],       v);
    v = fmaf(bufA[65*68 + j], w1p[64 + h],  v);
    v = fmaf(bufA[66*68 + j], w1p[128 + h], v);
    bufA[h*68 + j] = fmaxf(v + b1[h], 0.0f);
  }
  const int jg = t & 7, hg = t >> 3;
  const int j0 = jg << 3;
  const int c0 = hg << 3;             // stage2: 8j x 8c packed pairs
  v2f acc2p[8][4];                    // [c][jpair]
#pragma unroll
  for (int c = 0; c < 8; ++c)
#pragma unroll
    for (int jp = 0; jp < 4; ++jp) acc2p[c][jp] = (v2f){0.0f, 0.0f};
  for (int hc = 0; hc < 64; hc += 16) {
    __syncthreads();                  // h1T ready / prior chunk consumed
    for (int e = t; e < 16*128; e += 128) {
      int hh = e >> 7, c = e & 127;
      bufB[hh*136 + c] = W2[(size_t)(hc+hh)*128 + c];
    }
    __syncthreads();
#pragma unroll
    for (int h = 0; h < 16; ++h) {
      const float4 ja = *(const float4*)&bufA[(hc+h)*68 + j0];
      const float4 jb = *(const float4*)&bufA[(hc+h)*68 + j0 + 4];
      const float4 wa = *(const float4*)&bufB[h*136 + c0];
      const float4 wb = *(const float4*)&bufB[h*136 + c0 + 4];
      const v2f hj[4] = {{ja.x, ja.y}, {ja.z, ja.w}, {jb.x, jb.y}, {jb.z, jb.w}};
      const float wv[8] = {wa.x, wa.y, wa.z, wa.w, wb.x, wb.y, wb.z, wb.w};
#pragma unroll
      for (int c = 0; c < 8; ++c) {
        const v2f w2 = {wv[c], wv[c]};
#pragma unroll
        for (int jp = 0; jp < 4; ++jp)
          acc2p[c][jp] += w2 * hj[jp];          // v_pk_fma_f32
      }
    }
  }
  const int cntv = cnt_s;
  const float4 b2a = *(const float4*)&b2[c0];
  const float4 b2b = *(const float4*)&b2[c0 + 4];
  const float bv2[8] = {b2a.x, b2a.y, b2a.z, b2a.w, b2b.x, b2b.y, b2b.z, b2b.w};
  float best[8];
#pragma unroll
  for (int c = 0; c < 8; ++c) {
    float v = -3.402823466e+38f;
#pragma unroll
    for (int jp = 0; jp < 4; ++jp) {
      float h0v = fmaxf(acc2p[c][jp].x + bv2[c], 0.0f);
      float h1v = fmaxf(acc2p[c][jp].y + bv2[c], 0.0f);
      v = (j0 + 2*jp     < cntv) ? fmaxf(v, h0v) : v;
      v = (j0 + 2*jp + 1 < cntv) ? fmaxf(v, h1v) : v;
    }
    best[c] = v;
  }
#pragma unroll
  for (int off = 1; off < 8; off <<= 1)
#pragma unroll
    for (int c = 0; c < 8; ++c)
      best[c] = fmaxf(best[c], __shfl_xor(best[c], off));
  if (jg == 0) {
    float4 o0 = {best[0], best[1], best[2], best[3]};
    float4 o1 = {best[4], best[5], best[6], best[7]};
    *(float4*)&dout[(size_t)m*128 + c0] = o0;
    *(float4*)&dout[(size_t)m*128 + c0 + 4] = o1;
  }
}

// --------------------------------------------- K3b: legacy conv (fallback)
__global__ __launch_bounds__(128) void k_conv(
    const float* __restrict__ x, const float* __restrict__ pos,
    const float* __restrict__ W1, const float* __restrict__ b1,
    const float* __restrict__ W2, const float* __restrict__ b2,
    const unsigned short* __restrict__ nbr, const int* __restrict__ cntp,
    float* __restrict__ dout)
{
  __shared__ __align__(16) float bufA[68*68];
  __shared__ __align__(16) float bufB[68*68];
  __shared__ unsigned short nbr_s[64];
  __shared__ float qv[3];
  __shared__ int cnt_s;
  const int t = threadIdx.x;
  const int m = blockIdx.x;
  const int b = m >> 12;
  if (t < 64) nbr_s[t] = nbr[(size_t)m*KNB + t];
  else if (t == 64) cnt_s = cntp[m];
  else if (t >= 65 && t < 68) qv[t-65] = dout[POSOUT_OFF + (size_t)m*3 + (t-65)];
  for (int e = t; e < 67*64; e += 128) {
    int ch = e >> 6, h = e & 63;
    bufB[ch*68 + h] = W1[e];
  }
  __syncthreads();
  {
    const int ch = t & 63, jj = t >> 6;
    const size_t xb = (size_t)b * NPER * CIN;
    for (int j0 = 0; j0 < 64; j0 += 2) {
      int j = j0 + jj;
      int r = nbr_s[j];
      bufA[ch*68 + j] = x[xb + (size_t)r*CIN + ch];
    }
  }
  {
    const size_t pbb = (size_t)b * NPER * 3;
    for (int e = t; e < 192; e += 128) {
      int j = e & 63, d = e >> 6;
      int r = nbr_s[j];
      bufA[(64+d)*68 + j] = pos[pbb + (size_t)r*3 + d] - qv[d];
    }
  }
  __syncthreads();
  const int jg = t & 7, hg = t >> 3;
  const int j0 = jg << 3;
  const int h0 = hg << 2;
  v2f accp[4][4];
#pragma unroll
  for (int hh = 0; hh < 4; ++hh)
#pragma unroll
    for (int jp = 0; jp < 4; ++jp) accp[hh][jp] = (v2f){0.0f, 0.0f};
  for (int ch = 0; ch < 67; ++ch) {
    const float4 fa = *(const float4*)&bufA[ch*68 + j0];
    const float4 fb = *(const float4*)&bufA[ch*68 + j0 + 4];
    const float4 w  = *(const float4*)&bufB[ch*68 + h0];
    const v2f fj[4] = {{fa.x, fa.y}, {fa.z, fa.w}, {fb.x, fb.y}, {fb.z, fb.w}};
    const float ws4[4] = {w.x, w.y, w.z, w.w};
#pragma unroll
    for (int hh = 0; hh < 4; ++hh) {
      const v2f wv2 = {ws4[hh], ws4[hh]};
#pragma unroll
      for (int jp = 0; jp < 4; ++jp)
        accp[hh][jp] += wv2 * fj[jp];
    }
  }
  __syncthreads();
  {
    const float4 bb = *(const float4*)&b1[h0];
    const float bv[4] = {bb.x, bb.y, bb.z, bb.w};
#pragma unroll
    for (int hh = 0; hh < 4; ++hh) {
      float4 o0, o1;
      o0.x = fmaxf(accp[hh][0].x + bv[hh], 0.0f);
      o0.y = fmaxf(accp[hh][0].y + bv[hh], 0.0f);
      o0.z = fmaxf(accp[hh][1].x + bv[hh], 0.0f);
      o0.w = fmaxf(accp[hh][1].y + bv[hh], 0.0f);
      o1.x = fmaxf(accp[hh][2].x + bv[hh], 0.0f);
      o1.y = fmaxf(accp[hh][2].y + bv[hh], 0.0f);
      o1.z = fmaxf(accp[hh][3].x + bv[hh], 0.0f);
      o1.w = fmaxf(accp[hh][3].y + bv[hh], 0.0f);
      *(float4*)&bufA[(h0+hh)*68 + j0] = o0;
      *(float4*)&bufA[(h0+hh)*68 + j0 + 4] = o1;
    }
  }
  const int c0 = hg << 3;
  v2f acc2p[8][4];
#pragma unroll
  for (int c = 0; c < 8; ++c)
#pragma unroll
    for (int jp = 0; jp < 4; ++jp) acc2p[c][jp] = (v2f){0.0f, 0.0f};
  for (int hc = 0; hc < 64; hc += 16) {
    __syncthreads();
    for (int e = t; e < 16*128; e += 128) {
      int hh = e >> 7, c = e & 127;
      bufB[hh*136 + c] = W2[(size_t)(hc+hh)*128 + c];
    }
    __syncthreads();
#pragma unroll
    for (int h = 0; h < 16; ++h) {
      const float4 ja = *(const float4*)&bufA[(hc+h)*68 + j0];
      const float4 jb = *(const float4*)&bufA[(hc+h)*68 + j0 + 4];
      const float4 wa = *(const float4*)&bufB[h*136 + c0];
      const float4 wb = *(const float4*)&bufB[h*136 + c0 + 4];
      const v2f hj[4] = {{ja.x, ja.y}, {ja.z, ja.w}, {jb.x, jb.y}, {jb.z, jb.w}};
      const float wv[8] = {wa.x, wa.y, wa.z, wa.w, wb.x, wb.y, wb.z, wb.w};
#pragma unroll
      for (int c = 0; c < 8; ++c) {
        const v2f w2 = {wv[c], wv[c]};
#pragma unroll
        for (int jp = 0; jp < 4; ++jp)
          acc2p[c][jp] += w2 * hj[jp];
      }
    }
  }
  const int cntv = cnt_s;
  const float4 b2a = *(const float4*)&b2[c0];
  const float4 b2b = *(const float4*)&b2[c0 + 4];
  const float bv2[8] = {b2a.x, b2a.y, b2a.z, b2a.w, b2b.x, b2b.y, b2b.z, b2b.w};
  float best[8];
#pragma unroll
  for (int c = 0; c < 8; ++c) {
    float v = -3.402823466e+38f;
#pragma unroll
    for (int jp = 0; jp < 4; ++jp) {
      float h0v = fmaxf(acc2p[c][jp].x + bv2[c], 0.0f);
      float h1v = fmaxf(acc2p[c][jp].y + bv2[c], 0.0f);
      v = (j0 + 2*jp     < cntv) ? fmaxf(v, h0v) : v;
      v = (j0 + 2*jp + 1 < cntv) ? fmaxf(v, h1v) : v;
    }
    best[c] = v;
  }
#pragma unroll
  for (int off = 1; off < 8; off <<= 1)
#pragma unroll
    for (int c = 0; c < 8; ++c)
      best[c] = fmaxf(best[c], __shfl_xor(best[c], off));
  if (jg == 0) {
    float4 o0 = {best[0], best[1], best[2], best[3]};
    float4 o1 = {best[4], best[5], best[6], best[7]};
    *(float4*)&dout[(size_t)m*128 + c0] = o0;
    *(float4*)&dout[(size_t)m*128 + c0 + 4] = o1;
  }
}

extern "C" void kernel_launch(void* const* d_in, const int* in_sizes, int n_in,
                              void* d_out, int out_size, void* d_ws, size_t ws_size,
                              hipStream_t stream) {
  const float* x   = (const float*)d_in[0];
  const float* pos = (const float*)d_in[1];
  // d_in[2] = batch (layout known statically, unused)
  const float* W1  = (const float*)d_in[3];
  const float* b1  = (const float*)d_in[4];
  const float* W2  = (const float*)d_in[5];
  const float* b2  = (const float*)d_in[6];
  float* dout = (float*)d_out;
  unsigned short* nbr = (unsigned short*)d_ws;
  int* cnt = (int*)((char*)d_ws + (size_t)MTOT*KNB*2);
  float* hp = (float*)((char*)d_ws + PRE_OFF);
  const bool use_pre = (ws_size >= PRE_OFF + PRE_BYTES);  // constant per run

  hipLaunchKernelGGL(k_fps,    dim3(NB),     dim3(FPS_T), FPS_LDS, stream, pos, dout);
  hipLaunchKernelGGL(k_radius, dim3(MTOT/4), dim3(256),   0, stream, pos, dout, nbr, cnt);
  if (use_pre) {
    hipLaunchKernelGGL(k_pre,   dim3(NB*NPER/64), dim3(256), 0, stream, x, W1, hp);
    hipLaunchKernelGGL(k_conv2, dim3(MTOT),       dim3(128), 0, stream,
                       hp, pos, W1, b1, W2, b2, nbr, cnt, dout);
  } else {
    hipLaunchKernelGGL(k_conv,  dim3(MTOT),       dim3(128), 0, stream,
                       x, pos, W1, b1, W2, b2, nbr, cnt, dout);
  }
}